// Round 15
// baseline (406.238 us; speedup 1.0000x reference)
//
#include <hip/hip_runtime.h>
#include <hip/hip_bf16.h>

#define N_NODES 50000
#define N_EDGES 800000

typedef short  short8  __attribute__((ext_vector_type(8)));
typedef float  floatx4 __attribute__((ext_vector_type(4)));
typedef float  floatx2 __attribute__((ext_vector_type(2)));

__device__ __forceinline__ short f2bf(float f) {
    union { __hip_bfloat16 h; short s; } u;
    u.h = __float2bfloat16(f);
    return u.s;
}
__device__ __forceinline__ float2 upk(unsigned v) {
    union { float f; unsigned u; } a, b;
    a.u = v << 16; b.u = v & 0xffff0000u;
    return make_float2(a.f, b.f);
}
__device__ __forceinline__ unsigned packbf(float lo, float hi) {
    return ((unsigned)(unsigned short)f2bf(hi) << 16) | (unsigned short)f2bf(lo);
}
// fp8 e4m3 HW converts (gfx940+)
__device__ __forceinline__ unsigned pack4fp8(float a, float b, float c, float d) {
    int p = __builtin_amdgcn_cvt_pk_fp8_f32(a, b, 0, false);
    p = __builtin_amdgcn_cvt_pk_fp8_f32(c, d, p, true);
    return (unsigned)p;
}
__device__ __forceinline__ unsigned char fp8b(float v) {
    return (unsigned char)(__builtin_amdgcn_cvt_pk_fp8_f32(v, v, 0, false) & 0xff);
}

__device__ __forceinline__ void gld_lds16(const short* g, short* l) {
    __builtin_amdgcn_global_load_lds(
        (const __attribute__((address_space(1))) int*)g,
        (__attribute__((address_space(3))) int*)l, 16, 0, 0);
}

// ---------------------------------------------------------------- CSR build
__global__ void k_deg(const int* __restrict__ dst, int* __restrict__ deg) {
    int e = blockIdx.x * 256 + threadIdx.x;
    if (e < N_EDGES) atomicAdd(&deg[dst[e]], 1);
}

__global__ __launch_bounds__(1024) void k_scan1(const int* __restrict__ deg,
                                                int* __restrict__ bsum,
                                                float* __restrict__ dinv) {
    __shared__ int ws[16];
    int b = blockIdx.x, t = threadIdx.x, i = b * 1024 + t;
    int lane = t & 63, wid = t >> 6;
    int v = (i < N_NODES) ? deg[i] : 0;
    if (i < N_NODES) dinv[i] = 1.0f / fmaxf((float)v, 1.0f);
    int x = v;
    #pragma unroll
    for (int off = 1; off < 64; off <<= 1) x += __shfl_xor(x, off, 64);
    if (lane == 0) ws[wid] = x;
    __syncthreads();
    if (t == 0) {
        int s = 0;
        #pragma unroll
        for (int k = 0; k < 16; ++k) s += ws[k];
        bsum[b] = s;
    }
}

__global__ void k_scan2(const int* __restrict__ bsum, int* __restrict__ boff) {
    int lane = threadIdx.x;
    int v = (lane < 49) ? bsum[lane] : 0;
    int x = v;
    #pragma unroll
    for (int off = 1; off < 64; off <<= 1) {
        int y = __shfl_up(x, off, 64);
        if (lane >= off) x += y;
    }
    if (lane < 49) boff[lane] = x - v;
}

__global__ __launch_bounds__(1024) void k_scan3(const int* __restrict__ deg,
                                                const int* __restrict__ boff,
                                                int* __restrict__ rowptr,
                                                int* __restrict__ cursor) {
    __shared__ int ws[16];
    int b = blockIdx.x, t = threadIdx.x, i = b * 1024 + t;
    int lane = t & 63, wid = t >> 6;
    int v = (i < N_NODES) ? deg[i] : 0;
    int x = v;
    #pragma unroll
    for (int off = 1; off < 64; off <<= 1) {
        int y = __shfl_up(x, off, 64);
        if (lane >= off) x += y;
    }
    if (lane == 63) ws[wid] = x;
    __syncthreads();
    if (wid == 0) {
        int s = (lane < 16) ? ws[lane] : 0;
        #pragma unroll
        for (int off = 1; off < 16; off <<= 1) {
            int y = __shfl_up(s, off, 64);
            if (lane >= off) s += y;
        }
        if (lane < 16) ws[lane] = s;
    }
    __syncthreads();
    int waveOff = (wid == 0) ? 0 : ws[wid - 1];
    int incl = x + waveOff + boff[b];
    if (i < N_NODES) { rowptr[i + 1] = incl; cursor[i] = incl - v; }
    if (b == 0 && t == 0) rowptr[0] = 0;
}

__global__ void k_fill(const int* __restrict__ src, const int* __restrict__ dst,
                       int* __restrict__ cursor, int* __restrict__ col) {
    int e = blockIdx.x * 256 + threadIdx.x;
    if (e < N_EDGES) {
        int d = dst[e];
        int p = atomicAdd(&cursor[d], 1);
        col[p] = src[e];
    }
}

// ------------------------------------------- fused bf16/fp8 conversions
__global__ void k_cvt(const float* __restrict__ feat,
                      const float* __restrict__ W1s, const float* __restrict__ W1n,
                      const float* __restrict__ W2s, const float* __restrict__ W2n,
                      short* __restrict__ Abf, unsigned* __restrict__ F8u,
                      short* __restrict__ W1T, short* __restrict__ W2T) {
    int bb = blockIdx.x, t = threadIdx.x;
    if (bb < 6250) {
        int idx = bb * 256 + t;
        if (idx >= N_NODES * 32) return;
        int n = idx >> 5, c = (idx & 31) * 4;
        float4 v = *(const float4*)(feat + (size_t)n * 128 + c);
        *(short4*)(Abf + (size_t)n * 256 + c) =
            make_short4(f2bf(v.x), f2bf(v.y), f2bf(v.z), f2bf(v.w));
        F8u[(size_t)n * 32 + (c >> 2)] = pack4fp8(v.x, v.y, v.z, v.w);
    } else {
        int idx = (bb - 6250) * 256 + t;
        if (idx < 512 * 256) {
            int n = idx >> 8, k = idx & 255;
            float v = (k < 128) ? W1s[(size_t)k * 512 + n]
                                : W1n[(size_t)(k - 128) * 512 + n];
            W1T[idx] = f2bf(v);
        } else {
            int j = idx - 512 * 256;
            int n = j >> 9, k = j & 511;
            float v = (n < 128) ? W2s[(size_t)k * 128 + n]
                                : W2n[(size_t)k * 128 + (n - 128)];
            W2T[j] = f2bf(v);
        }
    }
}

// -------- fp8 gather core: 2 edges per load instruction. Lanes 0-31 carry
// edge 2j, lanes 32-63 edge 2j+1; per-lane base selected by cndmask of two
// readlane'd scalars (no LDS broadcast). Row = 32 uints (128 fp8 channels).
// Result: a[4] = channels 4*li..4*li+3, valid on lanes 0..31 after reduce.
template<int STRIDE>
__device__ __forceinline__ void wave_gather_fp8(
    const unsigned* __restrict__ U, const int* __restrict__ col,
    int s, int e, int lane, float a[4]) {
    const bool lo = lane < 32;
    const int li = lane & 31;
    a[0] = a[1] = a[2] = a[3] = 0.f;
    for (int base = s; base < e; base += 64) {
        int cnt = e - base; if (cnt > 64) cnt = 64;
        int myc = (base + lane < e) ? col[base + lane] : 0;
        int pairs = cnt >> 1;
        int j = 0;
        for (; j + 16 <= pairs; j += 16) {
            unsigned v[16];
            #pragma unroll
            for (int u = 0; u < 16; ++u) {
                int c0 = __builtin_amdgcn_readlane(myc, 2 * (j + u));
                int c1 = __builtin_amdgcn_readlane(myc, 2 * (j + u) + 1);
                int c = lo ? c0 : c1;
                v[u] = U[(size_t)c * STRIDE + li];
            }
            #pragma unroll
            for (int u = 0; u < 16; ++u) {
                floatx2 f01 = __builtin_amdgcn_cvt_pk_f32_fp8(v[u], false);
                floatx2 f23 = __builtin_amdgcn_cvt_pk_f32_fp8(v[u], true);
                a[0] += f01.x; a[1] += f01.y; a[2] += f23.x; a[3] += f23.y;
            }
        }
        for (; j + 8 <= pairs; j += 8) {
            unsigned v[8];
            #pragma unroll
            for (int u = 0; u < 8; ++u) {
                int c0 = __builtin_amdgcn_readlane(myc, 2 * (j + u));
                int c1 = __builtin_amdgcn_readlane(myc, 2 * (j + u) + 1);
                int c = lo ? c0 : c1;
                v[u] = U[(size_t)c * STRIDE + li];
            }
            #pragma unroll
            for (int u = 0; u < 8; ++u) {
                floatx2 f01 = __builtin_amdgcn_cvt_pk_f32_fp8(v[u], false);
                floatx2 f23 = __builtin_amdgcn_cvt_pk_f32_fp8(v[u], true);
                a[0] += f01.x; a[1] += f01.y; a[2] += f23.x; a[3] += f23.y;
            }
        }
        if (j < pairs) {
            unsigned v[8];
            int m = pairs - j;
            #pragma unroll
            for (int u = 0; u < 8; ++u) {
                if (u < m) {
                    int c0 = __builtin_amdgcn_readlane(myc, 2 * (j + u));
                    int c1 = __builtin_amdgcn_readlane(myc, 2 * (j + u) + 1);
                    int c = lo ? c0 : c1;
                    v[u] = U[(size_t)c * STRIDE + li];
                }
            }
            #pragma unroll
            for (int u = 0; u < 8; ++u) {
                if (u < m) {
                    floatx2 f01 = __builtin_amdgcn_cvt_pk_f32_fp8(v[u], false);
                    floatx2 f23 = __builtin_amdgcn_cvt_pk_f32_fp8(v[u], true);
                    a[0] += f01.x; a[1] += f01.y; a[2] += f23.x; a[3] += f23.y;
                }
            }
        }
        if (cnt & 1) {
            int c = __builtin_amdgcn_readlane(myc, cnt - 1);
            unsigned vv = U[(size_t)c * STRIDE + li];
            if (lo) {
                floatx2 f01 = __builtin_amdgcn_cvt_pk_f32_fp8(vv, false);
                floatx2 f23 = __builtin_amdgcn_cvt_pk_f32_fp8(vv, true);
                a[0] += f01.x; a[1] += f01.y; a[2] += f23.x; a[3] += f23.y;
            }
        }
    }
    #pragma unroll
    for (int k = 0; k < 4; ++k) a[k] += __shfl_xor(a[k], 32, 64);
}

// ---------------------------------------------- aggregation 1 (fp8 gather)
__global__ __launch_bounds__(256) void k_agg(
    const unsigned* __restrict__ F8u, const int* __restrict__ rowptr,
    const int* __restrict__ col, const float* __restrict__ dinv,
    unsigned* __restrict__ Aw) {
    int t = threadIdx.x, lane = t & 63, w = t >> 6;
    int n = blockIdx.x * 4 + w;
    int s = rowptr[n], e = rowptr[n + 1];
    float a[4];
    wave_gather_fp8<32>(F8u, col, s, e, lane, a);
    if (lane < 32) {
        float dv = dinv[n];
        uint2 o;
        o.x = packbf(a[0] * dv, a[1] * dv);
        o.y = packbf(a[2] * dv, a[3] * dv);
        *(uint2*)(Aw + (size_t)n * 128 + 64 + lane * 2) = o;
    }
}

// --------------------- aggregation 2 + bias/relu + MLP + softmax (fused)
__global__ __launch_bounds__(256) void k_aggmlp(
    const unsigned* __restrict__ Y8u, const int* __restrict__ rowptr,
    const int* __restrict__ col, const float* __restrict__ dinv,
    const unsigned* __restrict__ Zu, const float* __restrict__ b2,
    const float* __restrict__ Wp1, const float* __restrict__ bp1,
    const float* __restrict__ Wp2, const float* __restrict__ bp2,
    float* __restrict__ out) {
    __shared__ float h2sh[4][128];
    __shared__ float xsh[4][32];
    int t = threadIdx.x, lane = t & 63, w = t >> 6;
    int n = blockIdx.x * 4 + w;
    int s = rowptr[n], e = rowptr[n + 1];
    float a[4];
    wave_gather_fp8<32>(Y8u, col, s, e, lane, a);
    if (lane < 32) {
        float dv = dinv[n];
        uint2 zz = *(const uint2*)(Zu + (size_t)n * 64 + lane * 2);
        float2 z01 = upk(zz.x), z23 = upk(zz.y);
        float4 bb = *(const float4*)(b2 + lane * 4);
        h2sh[w][lane * 4 + 0] = fmaxf(z01.x + a[0] * dv + bb.x, 0.f);
        h2sh[w][lane * 4 + 1] = fmaxf(z01.y + a[1] * dv + bb.y, 0.f);
        h2sh[w][lane * 4 + 2] = fmaxf(z23.x + a[2] * dv + bb.z, 0.f);
        h2sh[w][lane * 4 + 3] = fmaxf(z23.y + a[3] * dv + bb.w, 0.f);
    }
    // intra-wave consumers only: no barrier needed (wave lockstep)
    int j = lane & 31, half = lane >> 5;
    float p = 0.f;
    #pragma unroll
    for (int k2 = 0; k2 < 64; ++k2) {
        int k = half * 64 + k2;
        p += h2sh[w][k] * Wp1[k * 32 + j];
    }
    p += __shfl_xor(p, 32, 64);
    if (half == 0) xsh[w][j] = fmaxf(p + bp1[j], 0.f);
    if (lane < 8) {
        float lg = bp2[lane];
        #pragma unroll
        for (int jj = 0; jj < 32; ++jj)
            lg += xsh[w][jj] * Wp2[jj * 8 + lane];
        float mx = lg;
        mx = fmaxf(mx, __shfl_xor(mx, 1, 64));
        mx = fmaxf(mx, __shfl_xor(mx, 2, 64));
        mx = fmaxf(mx, __shfl_xor(mx, 4, 64));
        float ev = expf(lg - mx);
        float sm = ev;
        sm += __shfl_xor(sm, 1, 64);
        sm += __shfl_xor(sm, 2, 64);
        sm += __shfl_xor(sm, 4, 64);
        out[(size_t)n * 8 + lane] = ev / sm;
    }
}

// ------------------------------------------------------- MFMA bf16 GEMM
// 128x128 tile. EPI1: h1bf bf16 (bias+relu, ldc=N) via LDS full-line stores.
// !EPI1: nBase<128 -> zbf bf16; nBase>=128 -> y1 fp8 (Y8, 128B rows).
template<int K, int N, bool EPI1>
__global__ __launch_bounds__(256) void k_gemm_mfma(
    const short* __restrict__ A, const short* __restrict__ BT,
    const float* __restrict__ bias, short* __restrict__ Obf,
    short* __restrict__ Obf2, unsigned char* __restrict__ Y8) {
    __shared__ short smem[2 * 128 * 32];
    short* sA = smem;
    short* sB = smem + 128 * 32;
    short* sOut = smem;                 // epilogue reuse
    unsigned char* sOutB = (unsigned char*)smem;
    const int t = threadIdx.x;
    const int lane = t & 63;
    const int w = t >> 6;
    const int mBase = blockIdx.x * 128;
    const int nBase = blockIdx.y * 128;
    const int mOff = (w & 1) * 64;
    const int nOff = (w >> 1) * 64;

    floatx4 zero4 = {0.f, 0.f, 0.f, 0.f};
    floatx4 acc[4][4];
    #pragma unroll
    for (int i = 0; i < 4; ++i)
        #pragma unroll
        for (int j = 0; j < 4; ++j) acc[i][j] = zero4;

    const int rL = lane >> 2;
    const int cg = (((lane & 3) ^ ((lane >> 3) & 3))) * 8;
    const int rA = w * 32 + rL;
    const long gA0 = (long)min(mBase + rA,      N_NODES - 1) * K + cg;
    const long gA1 = (long)min(mBase + rA + 16, N_NODES - 1) * K + cg;
    const long gB0 = (long)(nBase + rA)      * K + cg;
    const long gB1 = (long)(nBase + rA + 16) * K + cg;
    short* lA0 = sA + (w * 32) * 32;
    short* lA1 = sA + (w * 32 + 16) * 32;
    short* lB0 = sB + (w * 32) * 32;
    short* lB1 = sB + (w * 32 + 16) * 32;

    const int fr = lane & 15;
    const int csel = (((lane >> 4) ^ ((lane >> 1) & 3))) * 8;

    for (int kt = 0; kt < K / 32; ++kt) {
        const int k0 = kt * 32;
        __syncthreads();
        gld_lds16(A + gA0 + k0, lA0);
        gld_lds16(A + gA1 + k0, lA1);
        gld_lds16(BT + gB0 + k0, lB0);
        gld_lds16(BT + gB1 + k0, lB1);
        __syncthreads();
        short8 af[4], bf[4];
        #pragma unroll
        for (int i = 0; i < 4; ++i) {
            af[i] = *(const short8*)(sA + (mOff + i * 16 + fr) * 32 + csel);
            bf[i] = *(const short8*)(sB + (nOff + i * 16 + fr) * 32 + csel);
        }
        #pragma unroll
        for (int mi = 0; mi < 4; ++mi)
            #pragma unroll
            for (int ni = 0; ni < 4; ++ni)
                acc[mi][ni] = __builtin_amdgcn_mfma_f32_16x16x32_bf16(
                    af[mi], bf[ni], acc[mi][ni], 0, 0, 0);
    }

    // D frag layout: col = lane&15, row = (lane>>4)*4 + reg
    const int cn = lane & 15;
    const int cm = (lane >> 4) * 4;
    const int myh = mOff >> 6;
    const bool toFp8 = (!EPI1) && (nBase >= 128);

    float bv[4];
    #pragma unroll
    for (int ni = 0; ni < 4; ++ni)
        bv[ni] = EPI1 ? bias[nBase + nOff + ni * 16 + cn] : 0.f;
    const int ldc = EPI1 ? N : 128;
    const int cbase = EPI1 ? nBase : 0;
    short* target = EPI1 ? Obf : Obf2;
    for (int h = 0; h < 2; ++h) {
        __syncthreads();
        if (myh == h) {
            #pragma unroll
            for (int mi = 0; mi < 4; ++mi)
                #pragma unroll
                for (int ni = 0; ni < 4; ++ni)
                    #pragma unroll
                    for (int r = 0; r < 4; ++r) {
                        int mrow = mi * 16 + cm + r;
                        int nloc = nOff + ni * 16 + cn;
                        float v = acc[mi][ni][r];
                        if (EPI1) v = fmaxf(v + bv[ni], 0.f);
                        if (toFp8) sOutB[mrow * 128 + nloc] = fp8b(v);
                        else       sOut[mrow * 128 + nloc] = f2bf(v);
                    }
        }
        __syncthreads();
        if (toFp8) {
            // 64 rows x 128B: thread t -> row t>>1, 64B half (t&1), 4x16B
            int r0 = t >> 2, c0 = (t & 3) * 32;
            int m = mBase + h * 64 + r0;
            if (m < N_NODES) {
                const unsigned char* sp = sOutB + r0 * 128 + c0;
                unsigned char* gp = Y8 + (size_t)m * 128 + c0;
                *(short8*)(gp) = *(const short8*)(sp);
                *(short8*)(gp + 16) = *(const short8*)(sp + 16);
            }
        } else {
            int r0 = t >> 2, c0 = (t & 3) * 32;
            int m = mBase + h * 64 + r0;
            if (m < N_NODES) {
                const short* sp = sOut + r0 * 128 + c0;
                short* gp = target + (size_t)m * ldc + cbase + c0;
                #pragma unroll
                for (int q = 0; q < 4; ++q)
                    *(short8*)(gp + q * 8) = *(const short8*)(sp + q * 8);
            }
        }
    }
}

// ---------------------------------------------------------------- launch
extern "C" void kernel_launch(void* const* d_in, const int* in_sizes, int n_in,
                              void* d_out, int out_size, void* d_ws, size_t ws_size,
                              hipStream_t stream) {
    const float* feat   = (const float*)d_in[0];
    const int*   src    = (const int*)d_in[1];
    const int*   dst    = (const int*)d_in[2];
    const float* W1s    = (const float*)d_in[3];
    const float* W1n    = (const float*)d_in[4];
    const float* b1     = (const float*)d_in[5];
    const float* W2s    = (const float*)d_in[6];
    const float* W2n    = (const float*)d_in[7];
    const float* b2     = (const float*)d_in[8];
    const float* Wp1    = (const float*)d_in[9];
    const float* bp1    = (const float*)d_in[10];
    const float* Wp2    = (const float*)d_in[11];
    const float* bp2    = (const float*)d_in[12];
    float* out = (float*)d_out;

    char* w = (char*)d_ws;
    size_t off = 0;
    auto alloc = [&](size_t bytes) { char* p = w + off; off += (bytes + 255) & ~(size_t)255; return p; };
    int*   deg    = (int*)alloc(N_NODES * 4);
    int*   rowptr = (int*)alloc((N_NODES + 1) * 4);
    int*   cursor = (int*)alloc(N_NODES * 4);
    int*   col    = (int*)alloc(N_EDGES * 4);
    float* dinv   = (float*)alloc(N_NODES * 4);
    int*   bsum   = (int*)alloc(64 * 4);
    int*   boff   = (int*)alloc(64 * 4);
    short* Abf    = (short*)alloc((size_t)N_NODES * 256 * 2);   // [feat|agg1] bf16
    unsigned* F8u = (unsigned*)alloc((size_t)N_NODES * 128);    // feat fp8
    short* W1T    = (short*)alloc((size_t)512 * 256 * 2);
    short* W2T    = (short*)alloc((size_t)256 * 512 * 2);
    short* h1bf   = (short*)alloc((size_t)N_NODES * 512 * 2);
    short* zbf    = (short*)alloc((size_t)N_NODES * 128 * 2);
    unsigned char* y8 = (unsigned char*)alloc((size_t)N_NODES * 128);  // y1 fp8

    hipMemsetAsync(deg, 0, N_NODES * 4, stream);
    k_deg<<<N_EDGES / 256, 256, 0, stream>>>(dst, deg);
    k_scan1<<<49, 1024, 0, stream>>>(deg, bsum, dinv);
    k_scan2<<<1, 64, 0, stream>>>(bsum, boff);
    k_scan3<<<49, 1024, 0, stream>>>(deg, boff, rowptr, cursor);
    k_fill<<<N_EDGES / 256, 256, 0, stream>>>(src, dst, cursor, col);
    k_cvt<<<7274, 256, 0, stream>>>(feat, W1s, W1n, W2s, W2n, Abf, F8u, W1T, W2T);
    k_agg<<<N_NODES / 4, 256, 0, stream>>>(F8u, rowptr, col, dinv, (unsigned*)Abf);
    dim3 g1((N_NODES + 127) / 128, 4);
    k_gemm_mfma<256, 512, true><<<g1, 256, 0, stream>>>(Abf, W1T, b1, h1bf, nullptr, nullptr);
    dim3 g2((N_NODES + 127) / 128, 2);
    k_gemm_mfma<512, 256, false><<<g2, 256, 0, stream>>>(h1bf, W2T, nullptr, nullptr, zbf, y8);
    k_aggmlp<<<N_NODES / 4, 256, 0, stream>>>((const unsigned*)y8, rowptr, col, dinv,
                                              (const unsigned*)zbf, b2,
                                              Wp1, bp1, Wp2, bp2, out);
}

// Round 16
// 342.340 us; speedup vs baseline: 1.1867x; 1.1867x over previous
//
#include <hip/hip_runtime.h>
#include <hip/hip_bf16.h>

#define N_NODES 50000
#define N_EDGES 800000

typedef short  short8  __attribute__((ext_vector_type(8)));
typedef float  floatx4 __attribute__((ext_vector_type(4)));
typedef float  floatx2 __attribute__((ext_vector_type(2)));

__device__ __forceinline__ short f2bf(float f) {
    union { __hip_bfloat16 h; short s; } u;
    u.h = __float2bfloat16(f);
    return u.s;
}
__device__ __forceinline__ float2 upk(unsigned v) {
    union { float f; unsigned u; } a, b;
    a.u = v << 16; b.u = v & 0xffff0000u;
    return make_float2(a.f, b.f);
}
__device__ __forceinline__ unsigned packbf(float lo, float hi) {
    return ((unsigned)(unsigned short)f2bf(hi) << 16) | (unsigned short)f2bf(lo);
}
// fp8 e4m3 HW converts (gfx940+)
__device__ __forceinline__ unsigned pack4fp8(float a, float b, float c, float d) {
    int p = __builtin_amdgcn_cvt_pk_fp8_f32(a, b, 0, false);
    p = __builtin_amdgcn_cvt_pk_fp8_f32(c, d, p, true);
    return (unsigned)p;
}
__device__ __forceinline__ unsigned char fp8b(float v) {
    return (unsigned char)(__builtin_amdgcn_cvt_pk_fp8_f32(v, v, 0, false) & 0xff);
}

__device__ __forceinline__ void gld_lds16(const short* g, short* l) {
    __builtin_amdgcn_global_load_lds(
        (const __attribute__((address_space(1))) int*)g,
        (__attribute__((address_space(3))) int*)l, 16, 0, 0);
}

// ---------------------------------------------------------------- CSR build
__global__ void k_deg(const int* __restrict__ dst, int* __restrict__ deg) {
    int e = blockIdx.x * 256 + threadIdx.x;
    if (e < N_EDGES) atomicAdd(&deg[dst[e]], 1);
}

__global__ __launch_bounds__(1024) void k_scan1(const int* __restrict__ deg,
                                                int* __restrict__ bsum,
                                                float* __restrict__ dinv) {
    __shared__ int ws[16];
    int b = blockIdx.x, t = threadIdx.x, i = b * 1024 + t;
    int lane = t & 63, wid = t >> 6;
    int v = (i < N_NODES) ? deg[i] : 0;
    if (i < N_NODES) dinv[i] = 1.0f / fmaxf((float)v, 1.0f);
    int x = v;
    #pragma unroll
    for (int off = 1; off < 64; off <<= 1) x += __shfl_xor(x, off, 64);
    if (lane == 0) ws[wid] = x;
    __syncthreads();
    if (t == 0) {
        int s = 0;
        #pragma unroll
        for (int k = 0; k < 16; ++k) s += ws[k];
        bsum[b] = s;
    }
}

__global__ void k_scan2(const int* __restrict__ bsum, int* __restrict__ boff) {
    int lane = threadIdx.x;
    int v = (lane < 49) ? bsum[lane] : 0;
    int x = v;
    #pragma unroll
    for (int off = 1; off < 64; off <<= 1) {
        int y = __shfl_up(x, off, 64);
        if (lane >= off) x += y;
    }
    if (lane < 49) boff[lane] = x - v;
}

__global__ __launch_bounds__(1024) void k_scan3(const int* __restrict__ deg,
                                                const int* __restrict__ boff,
                                                int* __restrict__ rowptr,
                                                int* __restrict__ cursor) {
    __shared__ int ws[16];
    int b = blockIdx.x, t = threadIdx.x, i = b * 1024 + t;
    int lane = t & 63, wid = t >> 6;
    int v = (i < N_NODES) ? deg[i] : 0;
    int x = v;
    #pragma unroll
    for (int off = 1; off < 64; off <<= 1) {
        int y = __shfl_up(x, off, 64);
        if (lane >= off) x += y;
    }
    if (lane == 63) ws[wid] = x;
    __syncthreads();
    if (wid == 0) {
        int s = (lane < 16) ? ws[lane] : 0;
        #pragma unroll
        for (int off = 1; off < 16; off <<= 1) {
            int y = __shfl_up(s, off, 64);
            if (lane >= off) s += y;
        }
        if (lane < 16) ws[lane] = s;
    }
    __syncthreads();
    int waveOff = (wid == 0) ? 0 : ws[wid - 1];
    int incl = x + waveOff + boff[b];
    if (i < N_NODES) { rowptr[i + 1] = incl; cursor[i] = incl - v; }
    if (b == 0 && t == 0) rowptr[0] = 0;
}

__global__ void k_fill(const int* __restrict__ src, const int* __restrict__ dst,
                       int* __restrict__ cursor, int* __restrict__ col) {
    int e = blockIdx.x * 256 + threadIdx.x;
    if (e < N_EDGES) {
        int d = dst[e];
        int p = atomicAdd(&cursor[d], 1);
        col[p] = src[e];
    }
}

// ------------------------------------------- fused bf16/fp8 conversions
__global__ void k_cvt(const float* __restrict__ feat,
                      const float* __restrict__ W1s, const float* __restrict__ W1n,
                      const float* __restrict__ W2s, const float* __restrict__ W2n,
                      short* __restrict__ Abf, unsigned* __restrict__ F8u,
                      short* __restrict__ W1T, short* __restrict__ W2T) {
    int bb = blockIdx.x, t = threadIdx.x;
    if (bb < 6250) {
        int idx = bb * 256 + t;
        if (idx >= N_NODES * 32) return;
        int n = idx >> 5, c = (idx & 31) * 4;
        float4 v = *(const float4*)(feat + (size_t)n * 128 + c);
        *(short4*)(Abf + (size_t)n * 256 + c) =
            make_short4(f2bf(v.x), f2bf(v.y), f2bf(v.z), f2bf(v.w));
        F8u[(size_t)n * 32 + (c >> 2)] = pack4fp8(v.x, v.y, v.z, v.w);
    } else {
        int idx = (bb - 6250) * 256 + t;
        if (idx < 512 * 256) {
            int n = idx >> 8, k = idx & 255;
            float v = (k < 128) ? W1s[(size_t)k * 512 + n]
                                : W1n[(size_t)(k - 128) * 512 + n];
            W1T[idx] = f2bf(v);
        } else {
            int j = idx - 512 * 256;
            int n = j >> 9, k = j & 511;
            float v = (n < 128) ? W2s[(size_t)k * 128 + n]
                                : W2n[(size_t)k * 128 + (n - 128)];
            W2T[j] = f2bf(v);
        }
    }
}

// -------- fp8 gather core, round-8 structure: scalar-base (readlane) row
// loads, 16-deep. Row = 64 ushorts (128 fp8). Lane loads ushort -> 2 chans.
template<int STRIDE>   // stride in ushorts
__device__ __forceinline__ float2 wave_gather8(
    const unsigned short* __restrict__ U, const int* __restrict__ col,
    int s, int e, int lane) {
    float ax = 0.f, ay = 0.f;
    for (int base = s; base < e; base += 64) {
        int cnt = e - base; if (cnt > 64) cnt = 64;
        int myc = (base + lane < e) ? col[base + lane] : 0;
        int j = 0;
        for (; j + 16 <= cnt; j += 16) {
            unsigned short v[16];
            #pragma unroll
            for (int u = 0; u < 16; ++u) {
                int c = __builtin_amdgcn_readlane(myc, j + u);
                v[u] = U[(size_t)c * STRIDE + lane];
            }
            #pragma unroll
            for (int u = 0; u < 16; ++u) {
                floatx2 f = __builtin_amdgcn_cvt_pk_f32_fp8((unsigned)v[u], false);
                ax += f.x; ay += f.y;
            }
        }
        for (; j + 8 <= cnt; j += 8) {
            unsigned short v[8];
            #pragma unroll
            for (int u = 0; u < 8; ++u) {
                int c = __builtin_amdgcn_readlane(myc, j + u);
                v[u] = U[(size_t)c * STRIDE + lane];
            }
            #pragma unroll
            for (int u = 0; u < 8; ++u) {
                floatx2 f = __builtin_amdgcn_cvt_pk_f32_fp8((unsigned)v[u], false);
                ax += f.x; ay += f.y;
            }
        }
        if (j < cnt) {
            unsigned short v[8];
            int m = cnt - j;
            #pragma unroll
            for (int u = 0; u < 8; ++u) {
                if (u < m) {
                    int c = __builtin_amdgcn_readlane(myc, j + u);
                    v[u] = U[(size_t)c * STRIDE + lane];
                }
            }
            #pragma unroll
            for (int u = 0; u < 8; ++u) {
                if (u < m) {
                    floatx2 f = __builtin_amdgcn_cvt_pk_f32_fp8((unsigned)v[u], false);
                    ax += f.x; ay += f.y;
                }
            }
        }
    }
    return make_float2(ax, ay);
}

// ---------------------------------------------- aggregation 1 (fp8 gather)
__global__ __launch_bounds__(256) void k_agg(
    const unsigned short* __restrict__ F8, const int* __restrict__ rowptr,
    const int* __restrict__ col, const float* __restrict__ dinv,
    unsigned* __restrict__ Aw) {
    int t = threadIdx.x, lane = t & 63, w = t >> 6;
    int n = blockIdx.x * 4 + w;
    int s = rowptr[n], e = rowptr[n + 1];
    float2 a = wave_gather8<64>(F8, col, s, e, lane);
    float dv = dinv[n];
    Aw[(size_t)n * 128 + 64 + lane] = packbf(a.x * dv, a.y * dv);
}

// --------------------- aggregation 2 + bias/relu + MLP + softmax (fused)
__global__ __launch_bounds__(256) void k_aggmlp(
    const unsigned short* __restrict__ Y8, const int* __restrict__ rowptr,
    const int* __restrict__ col, const float* __restrict__ dinv,
    const unsigned* __restrict__ Zu, const float* __restrict__ b2,
    const float* __restrict__ Wp1, const float* __restrict__ bp1,
    const float* __restrict__ Wp2, const float* __restrict__ bp2,
    float* __restrict__ out) {
    __shared__ float h2sh[4][128];
    __shared__ float xsh[4][32];
    int t = threadIdx.x, lane = t & 63, w = t >> 6;
    int n = blockIdx.x * 4 + w;
    int s = rowptr[n], e = rowptr[n + 1];
    float2 a = wave_gather8<64>(Y8, col, s, e, lane);
    float dv = dinv[n];
    float2 zv = upk(Zu[(size_t)n * 64 + lane]);
    float2 bb = *(const float2*)(b2 + 2 * lane);
    h2sh[w][2 * lane]     = fmaxf(zv.x + a.x * dv + bb.x, 0.f);
    h2sh[w][2 * lane + 1] = fmaxf(zv.y + a.y * dv + bb.y, 0.f);
    // intra-wave consumers only: no barrier needed (wave lockstep)
    int j = lane & 31, half = lane >> 5;
    float p = 0.f;
    #pragma unroll
    for (int k2 = 0; k2 < 64; ++k2) {
        int k = half * 64 + k2;
        p += h2sh[w][k] * Wp1[k * 32 + j];
    }
    p += __shfl_xor(p, 32, 64);
    if (half == 0) xsh[w][j] = fmaxf(p + bp1[j], 0.f);
    if (lane < 8) {
        float lg = bp2[lane];
        #pragma unroll
        for (int jj = 0; jj < 32; ++jj)
            lg += xsh[w][jj] * Wp2[jj * 8 + lane];
        float mx = lg;
        mx = fmaxf(mx, __shfl_xor(mx, 1, 64));
        mx = fmaxf(mx, __shfl_xor(mx, 2, 64));
        mx = fmaxf(mx, __shfl_xor(mx, 4, 64));
        float ev = expf(lg - mx);
        float sm = ev;
        sm += __shfl_xor(sm, 1, 64);
        sm += __shfl_xor(sm, 2, 64);
        sm += __shfl_xor(sm, 4, 64);
        out[(size_t)n * 8 + lane] = ev / sm;
    }
}

// ------------------------------------------------------- MFMA bf16 GEMM
// 128x128 tile. EPI1: h1bf bf16 (bias+relu, ldc=N) via LDS full-line stores.
// !EPI1: nBase<128 -> zbf bf16; nBase>=128 -> y1 fp8 (Y8, 128B rows).
template<int K, int N, bool EPI1>
__global__ __launch_bounds__(256) void k_gemm_mfma(
    const short* __restrict__ A, const short* __restrict__ BT,
    const float* __restrict__ bias, short* __restrict__ Obf,
    short* __restrict__ Obf2, unsigned char* __restrict__ Y8) {
    __shared__ short smem[2 * 128 * 32];
    short* sA = smem;
    short* sB = smem + 128 * 32;
    short* sOut = smem;                 // epilogue reuse
    unsigned char* sOutB = (unsigned char*)smem;
    const int t = threadIdx.x;
    const int lane = t & 63;
    const int w = t >> 6;
    const int mBase = blockIdx.x * 128;
    const int nBase = blockIdx.y * 128;
    const int mOff = (w & 1) * 64;
    const int nOff = (w >> 1) * 64;

    floatx4 zero4 = {0.f, 0.f, 0.f, 0.f};
    floatx4 acc[4][4];
    #pragma unroll
    for (int i = 0; i < 4; ++i)
        #pragma unroll
        for (int j = 0; j < 4; ++j) acc[i][j] = zero4;

    const int rL = lane >> 2;
    const int cg = (((lane & 3) ^ ((lane >> 3) & 3))) * 8;
    const int rA = w * 32 + rL;
    const long gA0 = (long)min(mBase + rA,      N_NODES - 1) * K + cg;
    const long gA1 = (long)min(mBase + rA + 16, N_NODES - 1) * K + cg;
    const long gB0 = (long)(nBase + rA)      * K + cg;
    const long gB1 = (long)(nBase + rA + 16) * K + cg;
    short* lA0 = sA + (w * 32) * 32;
    short* lA1 = sA + (w * 32 + 16) * 32;
    short* lB0 = sB + (w * 32) * 32;
    short* lB1 = sB + (w * 32 + 16) * 32;

    const int fr = lane & 15;
    const int csel = (((lane >> 4) ^ ((lane >> 1) & 3))) * 8;

    for (int kt = 0; kt < K / 32; ++kt) {
        const int k0 = kt * 32;
        __syncthreads();
        gld_lds16(A + gA0 + k0, lA0);
        gld_lds16(A + gA1 + k0, lA1);
        gld_lds16(BT + gB0 + k0, lB0);
        gld_lds16(BT + gB1 + k0, lB1);
        __syncthreads();
        short8 af[4], bf[4];
        #pragma unroll
        for (int i = 0; i < 4; ++i) {
            af[i] = *(const short8*)(sA + (mOff + i * 16 + fr) * 32 + csel);
            bf[i] = *(const short8*)(sB + (nOff + i * 16 + fr) * 32 + csel);
        }
        #pragma unroll
        for (int mi = 0; mi < 4; ++mi)
            #pragma unroll
            for (int ni = 0; ni < 4; ++ni)
                acc[mi][ni] = __builtin_amdgcn_mfma_f32_16x16x32_bf16(
                    af[mi], bf[ni], acc[mi][ni], 0, 0, 0);
    }

    // D frag layout: col = lane&15, row = (lane>>4)*4 + reg
    const int cn = lane & 15;
    const int cm = (lane >> 4) * 4;
    const int myh = mOff >> 6;
    const bool toFp8 = (!EPI1) && (nBase >= 128);

    float bv[4];
    #pragma unroll
    for (int ni = 0; ni < 4; ++ni)
        bv[ni] = EPI1 ? bias[nBase + nOff + ni * 16 + cn] : 0.f;
    const int ldc = EPI1 ? N : 128;
    const int cbase = EPI1 ? nBase : 0;
    short* target = EPI1 ? Obf : Obf2;
    for (int h = 0; h < 2; ++h) {
        __syncthreads();
        if (myh == h) {
            #pragma unroll
            for (int mi = 0; mi < 4; ++mi)
                #pragma unroll
                for (int ni = 0; ni < 4; ++ni)
                    #pragma unroll
                    for (int r = 0; r < 4; ++r) {
                        int mrow = mi * 16 + cm + r;
                        int nloc = nOff + ni * 16 + cn;
                        float v = acc[mi][ni][r];
                        if (EPI1) v = fmaxf(v + bv[ni], 0.f);
                        if (toFp8) sOutB[mrow * 128 + nloc] = fp8b(v);
                        else       sOut[mrow * 128 + nloc] = f2bf(v);
                    }
        }
        __syncthreads();
        if (toFp8) {
            int r0 = t >> 2, c0 = (t & 3) * 32;
            int m = mBase + h * 64 + r0;
            if (m < N_NODES) {
                const unsigned char* sp = sOutB + r0 * 128 + c0;
                unsigned char* gp = Y8 + (size_t)m * 128 + c0;
                *(short8*)(gp) = *(const short8*)(sp);
                *(short8*)(gp + 16) = *(const short8*)(sp + 16);
            }
        } else {
            int r0 = t >> 2, c0 = (t & 3) * 32;
            int m = mBase + h * 64 + r0;
            if (m < N_NODES) {
                const short* sp = sOut + r0 * 128 + c0;
                short* gp = target + (size_t)m * ldc + cbase + c0;
                #pragma unroll
                for (int q = 0; q < 4; ++q)
                    *(short8*)(gp + q * 8) = *(const short8*)(sp + q * 8);
            }
        }
    }
}

// ---------------------------------------------------------------- launch
extern "C" void kernel_launch(void* const* d_in, const int* in_sizes, int n_in,
                              void* d_out, int out_size, void* d_ws, size_t ws_size,
                              hipStream_t stream) {
    const float* feat   = (const float*)d_in[0];
    const int*   src    = (const int*)d_in[1];
    const int*   dst    = (const int*)d_in[2];
    const float* W1s    = (const float*)d_in[3];
    const float* W1n    = (const float*)d_in[4];
    const float* b1     = (const float*)d_in[5];
    const float* W2s    = (const float*)d_in[6];
    const float* W2n    = (const float*)d_in[7];
    const float* b2     = (const float*)d_in[8];
    const float* Wp1    = (const float*)d_in[9];
    const float* bp1    = (const float*)d_in[10];
    const float* Wp2    = (const float*)d_in[11];
    const float* bp2    = (const float*)d_in[12];
    float* out = (float*)d_out;

    char* w = (char*)d_ws;
    size_t off = 0;
    auto alloc = [&](size_t bytes) { char* p = w + off; off += (bytes + 255) & ~(size_t)255; return p; };
    int*   deg    = (int*)alloc(N_NODES * 4);
    int*   rowptr = (int*)alloc((N_NODES + 1) * 4);
    int*   cursor = (int*)alloc(N_NODES * 4);
    int*   col    = (int*)alloc(N_EDGES * 4);
    float* dinv   = (float*)alloc(N_NODES * 4);
    int*   bsum   = (int*)alloc(64 * 4);
    int*   boff   = (int*)alloc(64 * 4);
    short* Abf    = (short*)alloc((size_t)N_NODES * 256 * 2);   // [feat|agg1] bf16
    unsigned* F8u = (unsigned*)alloc((size_t)N_NODES * 128);    // feat fp8
    short* W1T    = (short*)alloc((size_t)512 * 256 * 2);
    short* W2T    = (short*)alloc((size_t)256 * 512 * 2);
    short* h1bf   = (short*)alloc((size_t)N_NODES * 512 * 2);
    short* zbf    = (short*)alloc((size_t)N_NODES * 128 * 2);
    unsigned char* y8 = (unsigned char*)alloc((size_t)N_NODES * 128);  // y1 fp8

    hipMemsetAsync(deg, 0, N_NODES * 4, stream);
    k_deg<<<N_EDGES / 256, 256, 0, stream>>>(dst, deg);
    k_scan1<<<49, 1024, 0, stream>>>(deg, bsum, dinv);
    k_scan2<<<1, 64, 0, stream>>>(bsum, boff);
    k_scan3<<<49, 1024, 0, stream>>>(deg, boff, rowptr, cursor);
    k_fill<<<N_EDGES / 256, 256, 0, stream>>>(src, dst, cursor, col);
    k_cvt<<<7274, 256, 0, stream>>>(feat, W1s, W1n, W2s, W2n, Abf, F8u, W1T, W2T);
    k_agg<<<N_NODES / 4, 256, 0, stream>>>((const unsigned short*)F8u, rowptr, col, dinv,
                                           (unsigned*)Abf);
    dim3 g1((N_NODES + 127) / 128, 4);
    k_gemm_mfma<256, 512, true><<<g1, 256, 0, stream>>>(Abf, W1T, b1, h1bf, nullptr, nullptr);
    dim3 g2((N_NODES + 127) / 128, 2);
    k_gemm_mfma<512, 256, false><<<g2, 256, 0, stream>>>(h1bf, W2T, nullptr, nullptr, zbf, y8);
    k_aggmlp<<<N_NODES / 4, 256, 0, stream>>>((const unsigned short*)y8, rowptr, col, dinv,
                                              (const unsigned*)zbf, b2,
                                              Wp1, bp1, Wp2, bp2, out);
}

// Round 17
// 338.171 us; speedup vs baseline: 1.2013x; 1.0123x over previous
//
#include <hip/hip_runtime.h>
#include <hip/hip_bf16.h>

#define N_NODES 50000
#define N_EDGES 800000

typedef short  short8  __attribute__((ext_vector_type(8)));
typedef float  floatx4 __attribute__((ext_vector_type(4)));
typedef float  floatx2 __attribute__((ext_vector_type(2)));

__device__ __forceinline__ short f2bf(float f) {
    union { __hip_bfloat16 h; short s; } u;
    u.h = __float2bfloat16(f);
    return u.s;
}
__device__ __forceinline__ float2 upk(unsigned v) {
    union { float f; unsigned u; } a, b;
    a.u = v << 16; b.u = v & 0xffff0000u;
    return make_float2(a.f, b.f);
}
__device__ __forceinline__ unsigned packbf(float lo, float hi) {
    return ((unsigned)(unsigned short)f2bf(hi) << 16) | (unsigned short)f2bf(lo);
}
// fp8 e4m3 HW converts (gfx940+)
__device__ __forceinline__ unsigned pack4fp8(float a, float b, float c, float d) {
    int p = __builtin_amdgcn_cvt_pk_fp8_f32(a, b, 0, false);
    p = __builtin_amdgcn_cvt_pk_fp8_f32(c, d, p, true);
    return (unsigned)p;
}
__device__ __forceinline__ unsigned char fp8b(float v) {
    return (unsigned char)(__builtin_amdgcn_cvt_pk_fp8_f32(v, v, 0, false) & 0xff);
}

__device__ __forceinline__ void gld_lds16(const short* g, short* l) {
    __builtin_amdgcn_global_load_lds(
        (const __attribute__((address_space(1))) int*)g,
        (__attribute__((address_space(3))) int*)l, 16, 0, 0);
}

// ------------------------------------- merged deg + bf16/fp8 conversions
// blocks [0,3125): deg atomics; [3125,3125+6250): feat cvt; rest: weights.
__global__ void k_pre(const int* __restrict__ dst, int* __restrict__ deg,
                      const float* __restrict__ feat,
                      const float* __restrict__ W1s, const float* __restrict__ W1n,
                      const float* __restrict__ W2s, const float* __restrict__ W2n,
                      short* __restrict__ Abf, unsigned* __restrict__ F8u,
                      short* __restrict__ W1T, short* __restrict__ W2T) {
    int b = blockIdx.x, t = threadIdx.x;
    if (b < 3125) {
        int e = b * 256 + t;
        atomicAdd(&deg[dst[e]], 1);
        return;
    }
    int bb = b - 3125;
    if (bb < 6250) {
        int idx = bb * 256 + t;
        if (idx >= N_NODES * 32) return;
        int n = idx >> 5, c = (idx & 31) * 4;
        float4 v = *(const float4*)(feat + (size_t)n * 128 + c);
        *(short4*)(Abf + (size_t)n * 256 + c) =
            make_short4(f2bf(v.x), f2bf(v.y), f2bf(v.z), f2bf(v.w));
        F8u[(size_t)n * 32 + (c >> 2)] = pack4fp8(v.x, v.y, v.z, v.w);
    } else {
        int idx = (bb - 6250) * 256 + t;
        if (idx < 512 * 256) {
            int n = idx >> 8, k = idx & 255;
            float v = (k < 128) ? W1s[(size_t)k * 512 + n]
                                : W1n[(size_t)(k - 128) * 512 + n];
            W1T[idx] = f2bf(v);
        } else {
            int j = idx - 512 * 256;
            int n = j >> 9, k = j & 511;
            float v = (n < 128) ? W2s[(size_t)k * 128 + n]
                                : W2n[(size_t)k * 128 + (n - 128)];
            W2T[j] = f2bf(v);
        }
    }
}

__global__ __launch_bounds__(1024) void k_scan1(const int* __restrict__ deg,
                                                int* __restrict__ bsum,
                                                float* __restrict__ dinv) {
    __shared__ int ws[16];
    int b = blockIdx.x, t = threadIdx.x, i = b * 1024 + t;
    int lane = t & 63, wid = t >> 6;
    int v = (i < N_NODES) ? deg[i] : 0;
    if (i < N_NODES) dinv[i] = 1.0f / fmaxf((float)v, 1.0f);
    int x = v;
    #pragma unroll
    for (int off = 1; off < 64; off <<= 1) x += __shfl_xor(x, off, 64);
    if (lane == 0) ws[wid] = x;
    __syncthreads();
    if (t == 0) {
        int s = 0;
        #pragma unroll
        for (int k = 0; k < 16; ++k) s += ws[k];
        bsum[b] = s;
    }
}

__global__ void k_scan2(const int* __restrict__ bsum, int* __restrict__ boff) {
    int lane = threadIdx.x;
    int v = (lane < 49) ? bsum[lane] : 0;
    int x = v;
    #pragma unroll
    for (int off = 1; off < 64; off <<= 1) {
        int y = __shfl_up(x, off, 64);
        if (lane >= off) x += y;
    }
    if (lane < 49) boff[lane] = x - v;
}

__global__ __launch_bounds__(1024) void k_scan3(const int* __restrict__ deg,
                                                const int* __restrict__ boff,
                                                int* __restrict__ rowptr,
                                                int* __restrict__ cursor) {
    __shared__ int ws[16];
    int b = blockIdx.x, t = threadIdx.x, i = b * 1024 + t;
    int lane = t & 63, wid = t >> 6;
    int v = (i < N_NODES) ? deg[i] : 0;
    int x = v;
    #pragma unroll
    for (int off = 1; off < 64; off <<= 1) {
        int y = __shfl_up(x, off, 64);
        if (lane >= off) x += y;
    }
    if (lane == 63) ws[wid] = x;
    __syncthreads();
    if (wid == 0) {
        int s = (lane < 16) ? ws[lane] : 0;
        #pragma unroll
        for (int off = 1; off < 16; off <<= 1) {
            int y = __shfl_up(s, off, 64);
            if (lane >= off) s += y;
        }
        if (lane < 16) ws[lane] = s;
    }
    __syncthreads();
    int waveOff = (wid == 0) ? 0 : ws[wid - 1];
    int incl = x + waveOff + boff[b];
    if (i < N_NODES) { rowptr[i + 1] = incl; cursor[i] = incl - v; }
    if (b == 0 && t == 0) rowptr[0] = 0;
}

__global__ void k_fill(const int* __restrict__ src, const int* __restrict__ dst,
                       int* __restrict__ cursor, int* __restrict__ col) {
    int e = blockIdx.x * 256 + threadIdx.x;
    if (e < N_EDGES) {
        int d = dst[e];
        int p = atomicAdd(&cursor[d], 1);
        col[p] = src[e];
    }
}

// -------- fp8 gather core (round-8 structure): scalar-base (readlane) row
// loads, 16-deep. Row = 64 ushorts (128 fp8). Transaction-bound ~57us.
template<int STRIDE>
__device__ __forceinline__ float2 wave_gather8(
    const unsigned short* __restrict__ U, const int* __restrict__ col,
    int s, int e, int lane) {
    float ax = 0.f, ay = 0.f;
    for (int base = s; base < e; base += 64) {
        int cnt = e - base; if (cnt > 64) cnt = 64;
        int myc = (base + lane < e) ? col[base + lane] : 0;
        int j = 0;
        for (; j + 16 <= cnt; j += 16) {
            unsigned short v[16];
            #pragma unroll
            for (int u = 0; u < 16; ++u) {
                int c = __builtin_amdgcn_readlane(myc, j + u);
                v[u] = U[(size_t)c * STRIDE + lane];
            }
            #pragma unroll
            for (int u = 0; u < 16; ++u) {
                floatx2 f = __builtin_amdgcn_cvt_pk_f32_fp8((unsigned)v[u], false);
                ax += f.x; ay += f.y;
            }
        }
        for (; j + 8 <= cnt; j += 8) {
            unsigned short v[8];
            #pragma unroll
            for (int u = 0; u < 8; ++u) {
                int c = __builtin_amdgcn_readlane(myc, j + u);
                v[u] = U[(size_t)c * STRIDE + lane];
            }
            #pragma unroll
            for (int u = 0; u < 8; ++u) {
                floatx2 f = __builtin_amdgcn_cvt_pk_f32_fp8((unsigned)v[u], false);
                ax += f.x; ay += f.y;
            }
        }
        if (j < cnt) {
            unsigned short v[8];
            int m = cnt - j;
            #pragma unroll
            for (int u = 0; u < 8; ++u) {
                if (u < m) {
                    int c = __builtin_amdgcn_readlane(myc, j + u);
                    v[u] = U[(size_t)c * STRIDE + lane];
                }
            }
            #pragma unroll
            for (int u = 0; u < 8; ++u) {
                if (u < m) {
                    floatx2 f = __builtin_amdgcn_cvt_pk_f32_fp8((unsigned)v[u], false);
                    ax += f.x; ay += f.y;
                }
            }
        }
    }
    return make_float2(ax, ay);
}

// ---------------------------------------------- aggregation 1 (fp8 gather)
__global__ __launch_bounds__(256) void k_agg(
    const unsigned short* __restrict__ F8, const int* __restrict__ rowptr,
    const int* __restrict__ col, const float* __restrict__ dinv,
    unsigned* __restrict__ Aw) {
    int t = threadIdx.x, lane = t & 63, w = t >> 6;
    int n = blockIdx.x * 4 + w;
    int s = rowptr[n], e = rowptr[n + 1];
    float2 a = wave_gather8<64>(F8, col, s, e, lane);
    float dv = dinv[n];
    Aw[(size_t)n * 128 + 64 + lane] = packbf(a.x * dv, a.y * dv);
}

// --------------------- aggregation 2 + bias/relu + MLP + softmax (fused)
__global__ __launch_bounds__(256) void k_aggmlp(
    const unsigned short* __restrict__ Y8, const int* __restrict__ rowptr,
    const int* __restrict__ col, const float* __restrict__ dinv,
    const unsigned* __restrict__ Zu, const float* __restrict__ b2,
    const float* __restrict__ Wp1, const float* __restrict__ bp1,
    const float* __restrict__ Wp2, const float* __restrict__ bp2,
    float* __restrict__ out) {
    __shared__ float h2sh[4][128];
    __shared__ float xsh[4][32];
    int t = threadIdx.x, lane = t & 63, w = t >> 6;
    int n = blockIdx.x * 4 + w;
    int s = rowptr[n], e = rowptr[n + 1];
    float2 a = wave_gather8<64>(Y8, col, s, e, lane);
    float dv = dinv[n];
    float2 zv = upk(Zu[(size_t)n * 64 + lane]);
    float2 bb = *(const float2*)(b2 + 2 * lane);
    h2sh[w][2 * lane]     = fmaxf(zv.x + a.x * dv + bb.x, 0.f);
    h2sh[w][2 * lane + 1] = fmaxf(zv.y + a.y * dv + bb.y, 0.f);
    // intra-wave consumers only: no barrier needed (wave lockstep)
    int j = lane & 31, half = lane >> 5;
    float p = 0.f;
    #pragma unroll
    for (int k2 = 0; k2 < 64; ++k2) {
        int k = half * 64 + k2;
        p += h2sh[w][k] * Wp1[k * 32 + j];
    }
    p += __shfl_xor(p, 32, 64);
    if (half == 0) xsh[w][j] = fmaxf(p + bp1[j], 0.f);
    if (lane < 8) {
        float lg = bp2[lane];
        #pragma unroll
        for (int jj = 0; jj < 32; ++jj)
            lg += xsh[w][jj] * Wp2[jj * 8 + lane];
        float mx = lg;
        mx = fmaxf(mx, __shfl_xor(mx, 1, 64));
        mx = fmaxf(mx, __shfl_xor(mx, 2, 64));
        mx = fmaxf(mx, __shfl_xor(mx, 4, 64));
        float ev = expf(lg - mx);
        float sm = ev;
        sm += __shfl_xor(sm, 1, 64);
        sm += __shfl_xor(sm, 2, 64);
        sm += __shfl_xor(sm, 4, 64);
        out[(size_t)n * 8 + lane] = ev / sm;
    }
}

// ------------------------------------------------------- MFMA bf16 GEMM
// 128x128 tile, BK=64 via two 32-k stages per barrier pair (halves barrier
// count vs BK=32; per-stage LDS geometry identical to the proven layout).
// EPI1: h1bf bf16 (bias+relu, ldc=N). !EPI1: nBase<128 -> zbf; else y1 fp8.
template<int K, int N, bool EPI1>
__global__ __launch_bounds__(256) void k_gemm_mfma(
    const short* __restrict__ A, const short* __restrict__ BT,
    const float* __restrict__ bias, short* __restrict__ Obf,
    short* __restrict__ Obf2, unsigned char* __restrict__ Y8) {
    __shared__ short smem[4 * 128 * 32];   // 32 KB: sA[2 halves] + sB[2 halves]
    short* sOut = smem;                    // epilogue reuse (16 KB)
    unsigned char* sOutB = (unsigned char*)smem;
    const int t = threadIdx.x;
    const int lane = t & 63;
    const int w = t >> 6;
    const int mBase = blockIdx.x * 128;
    const int nBase = blockIdx.y * 128;
    const int mOff = (w & 1) * 64;
    const int nOff = (w >> 1) * 64;

    floatx4 zero4 = {0.f, 0.f, 0.f, 0.f};
    floatx4 acc[4][4];
    #pragma unroll
    for (int i = 0; i < 4; ++i)
        #pragma unroll
        for (int j = 0; j < 4; ++j) acc[i][j] = zero4;

    const int rL = lane >> 2;
    const int cg = (((lane & 3) ^ ((lane >> 3) & 3))) * 8;
    const int rA = w * 32 + rL;
    const long gA0 = (long)min(mBase + rA,      N_NODES - 1) * K + cg;
    const long gA1 = (long)min(mBase + rA + 16, N_NODES - 1) * K + cg;
    const long gB0 = (long)(nBase + rA)      * K + cg;
    const long gB1 = (long)(nBase + rA + 16) * K + cg;

    const int fr = lane & 15;
    const int csel = (((lane >> 4) ^ ((lane >> 1) & 3))) * 8;

    for (int kt = 0; kt < K / 64; ++kt) {
        __syncthreads();
        #pragma unroll
        for (int hh = 0; hh < 2; ++hh) {
            const int k0 = kt * 64 + hh * 32;
            short* sA = smem + hh * 4096;
            short* sB = smem + 8192 + hh * 4096;
            gld_lds16(A + gA0 + k0, sA + (w * 32) * 32);
            gld_lds16(A + gA1 + k0, sA + (w * 32 + 16) * 32);
            gld_lds16(BT + gB0 + k0, sB + (w * 32) * 32);
            gld_lds16(BT + gB1 + k0, sB + (w * 32 + 16) * 32);
        }
        __syncthreads();
        #pragma unroll
        for (int hh = 0; hh < 2; ++hh) {
            const short* sA = smem + hh * 4096;
            const short* sB = smem + 8192 + hh * 4096;
            short8 af[4], bf[4];
            #pragma unroll
            for (int i = 0; i < 4; ++i) {
                af[i] = *(const short8*)(sA + (mOff + i * 16 + fr) * 32 + csel);
                bf[i] = *(const short8*)(sB + (nOff + i * 16 + fr) * 32 + csel);
            }
            #pragma unroll
            for (int mi = 0; mi < 4; ++mi)
                #pragma unroll
                for (int ni = 0; ni < 4; ++ni)
                    acc[mi][ni] = __builtin_amdgcn_mfma_f32_16x16x32_bf16(
                        af[mi], bf[ni], acc[mi][ni], 0, 0, 0);
        }
    }

    // D frag layout: col = lane&15, row = (lane>>4)*4 + reg
    const int cn = lane & 15;
    const int cm = (lane >> 4) * 4;
    const int myh = mOff >> 6;
    const bool toFp8 = (!EPI1) && (nBase >= 128);

    float bv[4];
    #pragma unroll
    for (int ni = 0; ni < 4; ++ni)
        bv[ni] = EPI1 ? bias[nBase + nOff + ni * 16 + cn] : 0.f;
    const int ldc = EPI1 ? N : 128;
    const int cbase = EPI1 ? nBase : 0;
    short* target = EPI1 ? Obf : Obf2;
    for (int h = 0; h < 2; ++h) {
        __syncthreads();
        if (myh == h) {
            #pragma unroll
            for (int mi = 0; mi < 4; ++mi)
                #pragma unroll
                for (int ni = 0; ni < 4; ++ni)
                    #pragma unroll
                    for (int r = 0; r < 4; ++r) {
                        int mrow = mi * 16 + cm + r;
                        int nloc = nOff + ni * 16 + cn;
                        float v = acc[mi][ni][r];
                        if (EPI1) v = fmaxf(v + bv[ni], 0.f);
                        if (toFp8) sOutB[mrow * 128 + nloc] = fp8b(v);
                        else       sOut[mrow * 128 + nloc] = f2bf(v);
                    }
        }
        __syncthreads();
        if (toFp8) {
            int r0 = t >> 2, c0 = (t & 3) * 32;
            int m = mBase + h * 64 + r0;
            if (m < N_NODES) {
                const unsigned char* sp = sOutB + r0 * 128 + c0;
                unsigned char* gp = Y8 + (size_t)m * 128 + c0;
                *(short8*)(gp) = *(const short8*)(sp);
                *(short8*)(gp + 16) = *(const short8*)(sp + 16);
            }
        } else {
            int r0 = t >> 2, c0 = (t & 3) * 32;
            int m = mBase + h * 64 + r0;
            if (m < N_NODES) {
                const short* sp = sOut + r0 * 128 + c0;
                short* gp = target + (size_t)m * ldc + cbase + c0;
                #pragma unroll
                for (int q = 0; q < 4; ++q)
                    *(short8*)(gp + q * 8) = *(const short8*)(sp + q * 8);
            }
        }
    }
}

// ---------------------------------------------------------------- launch
extern "C" void kernel_launch(void* const* d_in, const int* in_sizes, int n_in,
                              void* d_out, int out_size, void* d_ws, size_t ws_size,
                              hipStream_t stream) {
    const float* feat   = (const float*)d_in[0];
    const int*   src    = (const int*)d_in[1];
    const int*   dst    = (const int*)d_in[2];
    const float* W1s    = (const float*)d_in[3];
    const float* W1n    = (const float*)d_in[4];
    const float* b1     = (const float*)d_in[5];
    const float* W2s    = (const float*)d_in[6];
    const float* W2n    = (const float*)d_in[7];
    const float* b2     = (const float*)d_in[8];
    const float* Wp1    = (const float*)d_in[9];
    const float* bp1    = (const float*)d_in[10];
    const float* Wp2    = (const float*)d_in[11];
    const float* bp2    = (const float*)d_in[12];
    float* out = (float*)d_out;

    char* w = (char*)d_ws;
    size_t off = 0;
    auto alloc = [&](size_t bytes) { char* p = w + off; off += (bytes + 255) & ~(size_t)255; return p; };
    int*   deg    = (int*)alloc(N_NODES * 4);
    int*   rowptr = (int*)alloc((N_NODES + 1) * 4);
    int*   cursor = (int*)alloc(N_NODES * 4);
    int*   col    = (int*)alloc(N_EDGES * 4);
    float* dinv   = (float*)alloc(N_NODES * 4);
    int*   bsum   = (int*)alloc(64 * 4);
    int*   boff   = (int*)alloc(64 * 4);
    short* Abf    = (short*)alloc((size_t)N_NODES * 256 * 2);   // [feat|agg1] bf16
    unsigned* F8u = (unsigned*)alloc((size_t)N_NODES * 128);    // feat fp8
    short* W1T    = (short*)alloc((size_t)512 * 256 * 2);
    short* W2T    = (short*)alloc((size_t)256 * 512 * 2);
    short* h1bf   = (short*)alloc((size_t)N_NODES * 512 * 2);
    short* zbf    = (short*)alloc((size_t)N_NODES * 128 * 2);
    unsigned char* y8 = (unsigned char*)alloc((size_t)N_NODES * 128);  // y1 fp8

    hipMemsetAsync(deg, 0, N_NODES * 4, stream);
    k_pre<<<3125 + 7274, 256, 0, stream>>>(dst, deg, feat, W1s, W1n, W2s, W2n,
                                           Abf, F8u, W1T, W2T);
    k_scan1<<<49, 1024, 0, stream>>>(deg, bsum, dinv);
    k_scan2<<<1, 64, 0, stream>>>(bsum, boff);
    k_scan3<<<49, 1024, 0, stream>>>(deg, boff, rowptr, cursor);
    k_fill<<<N_EDGES / 256, 256, 0, stream>>>(src, dst, cursor, col);
    k_agg<<<N_NODES / 4, 256, 0, stream>>>((const unsigned short*)F8u, rowptr, col, dinv,
                                           (unsigned*)Abf);
    dim3 g1((N_NODES + 127) / 128, 4);
    k_gemm_mfma<256, 512, true><<<g1, 256, 0, stream>>>(Abf, W1T, b1, h1bf, nullptr, nullptr);
    dim3 g2((N_NODES + 127) / 128, 2);
    k_gemm_mfma<512, 256, false><<<g2, 256, 0, stream>>>(h1bf, W2T, nullptr, nullptr, zbf, y8);
    k_aggmlp<<<N_NODES / 4, 256, 0, stream>>>((const unsigned short*)y8, rowptr, col, dinv,
                                              (const unsigned*)zbf, b2,
                                              Wp1, bp1, Wp2, bp2, out);
}